// Round 4
// baseline (37.536 us; speedup 1.0000x reference)
//
#include <hip/hip_runtime.h>

// Fixed problem constants
#define NFFT  4096
#define HOP   1024
#define T_IN  441000          // samples per (b,c)
#define L1    444416          // after 1st reflect pad
#define PAD1  1536
#define P2    2048
#define NSEG  436             // hop segments 0..435 (we use 2..435)
#define BC    16              // B*C
#define POS0  3584            // output g -> OLA position g + 3584
#define F_LO  2
#define F_HI  432

// sin/cos of 2*pi*f, f in revolutions (exact for our dyadic fractions)
#if __has_builtin(__builtin_amdgcn_cosf)
#define COS2PI(f) __builtin_amdgcn_cosf(f)
#define SIN2PI(f) __builtin_amdgcn_sinf(f)
#else
#define COS2PI(f) __cosf(6.28318530717958647692f * (f))
#define SIN2PI(f) __sinf(6.28318530717958647692f * (f))
#endif

// angle-addition constants for +i/4096 revolutions (i = 1,2,3)
#define CD1 0.99999882345139f
#define SD1 0.00153398018606f
#define CD2 0.99999529380610f
#define SD2 0.00306795676122f
#define CD3 0.99998941106312f
#define SD3 0.00460192611794f

// Composed reflect-pads: xpad[m] = x[map_idx(m)]
__device__ __forceinline__ int map_idx(int m) {
    int a = m - P2;
    if (a < 0) a = -a;
    else if (a >= L1) a = 2 * L1 - 2 - a;
    int b = a - PAD1;
    if (b < 0) b = -b;
    else if (b >= T_IN) b = 2 * T_IN - 2 - b;
    return b;
}

// Segment partials: per segment s (1024 samples), for each window quarter q:
//   P[bc][s][2q+par] = sum_{n_local, parity par} xpad[1024 s + n_local] * win[1024 q + n_local]
// One wave per (s, bc); x read once, window values generated by sincos.
__global__ void __launch_bounds__(256) seg_partials_kernel(const float* __restrict__ x,
                                                           float* __restrict__ P) {
    const int wave = threadIdx.x >> 6;
    const int lane = threadIdx.x & 63;
    const int s = 2 + blockIdx.x * 4 + wave;
    if (s > 435) return;
    const int bc = blockIdx.y;
    const float* xb = x + (size_t)bc * T_IN;
    const int base = s * HOP - POS0;            // identity x index at n_local=0
    const bool fastseg = (s >= 4 && s <= 433);  // no reflection inside segment
    float sE0=0,sE1=0,sE2=0,sE3=0,sO0=0,sO1=0,sO2=0,sO3=0;
    #pragma unroll
    for (int i = 0; i < 4; ++i) {
        const int nl = i * 256 + lane * 4;      // 0..1023, coalesced float4
        float4 xv;
        if (fastseg) {
            xv = *reinterpret_cast<const float4*>(xb + base + nl);
        } else {
            const int m = s * HOP + nl;
            xv.x = xb[map_idx(m)];     xv.y = xb[map_idx(m + 1)];
            xv.z = xb[map_idx(m + 2)]; xv.w = xb[map_idx(m + 3)];
        }
        // theta = 2*pi*(nl+c)/4096 ; quarters: win[n]=.5-.5cos, win[n+1024]=.5+.5sin,
        // win[n+2048]=.5+.5cos, win[n+3072]=.5-.5sin
        const float frac = (float)nl * (1.0f / 4096.0f);
        const float cs0 = COS2PI(frac), sn0 = SIN2PI(frac);
        const float cs[4] = { cs0, fmaf(cs0, CD1, -sn0 * SD1),
                                   fmaf(cs0, CD2, -sn0 * SD2),
                                   fmaf(cs0, CD3, -sn0 * SD3) };
        const float sn[4] = { sn0, fmaf(sn0, CD1,  cs0 * SD1),
                                   fmaf(sn0, CD2,  cs0 * SD2),
                                   fmaf(sn0, CD3,  cs0 * SD3) };
        const float xc[4] = { xv.x, xv.y, xv.z, xv.w };
        #pragma unroll
        for (int c = 0; c < 4; ++c) {
            const float w0 = fmaf(-0.5f, cs[c], 0.5f);
            const float w1 = fmaf( 0.5f, sn[c], 0.5f);
            const float w2 = fmaf( 0.5f, cs[c], 0.5f);
            const float w3 = fmaf(-0.5f, sn[c], 0.5f);
            if ((c & 1) == 0) {
                sE0 = fmaf(xc[c], w0, sE0); sE1 = fmaf(xc[c], w1, sE1);
                sE2 = fmaf(xc[c], w2, sE2); sE3 = fmaf(xc[c], w3, sE3);
            } else {
                sO0 = fmaf(xc[c], w0, sO0); sO1 = fmaf(xc[c], w1, sO1);
                sO2 = fmaf(xc[c], w2, sO2); sO3 = fmaf(xc[c], w3, sO3);
            }
        }
    }
    #pragma unroll
    for (int off = 32; off; off >>= 1) {
        sE0 += __shfl_down(sE0, off, 64); sO0 += __shfl_down(sO0, off, 64);
        sE1 += __shfl_down(sE1, off, 64); sO1 += __shfl_down(sO1, off, 64);
        sE2 += __shfl_down(sE2, off, 64); sO2 += __shfl_down(sO2, off, 64);
        sE3 += __shfl_down(sE3, off, 64); sO3 += __shfl_down(sO3, off, 64);
    }
    if (lane == 0) {
        float* Pp = P + ((size_t)bc * NSEG + s) * 8;   // [E0,O0,E1,O1,E2,O2,E3,O3]
        Pp[0]=sE0; Pp[1]=sO0; Pp[2]=sE1; Pp[3]=sO1;
        Pp[4]=sE2; Pp[5]=sO2; Pp[6]=sE3; Pp[7]=sO3;
    }
}

// Main: out[g] = (2/3) * sum_{j covering pos} win[t] * (2048*win[t]*x[2048j-3072-g] + p_j)
// t = pos-1024j; win via sincos (win[t] cycles cos/sin/-cos/-sin with j mod 4);
// p_j = E_j (t odd) else O_j, E/O recombined from quarter partials P.
// 1024 outputs per block, 4 per thread (float4 store). jlo split at idx 512 = wave boundary.
__global__ void __launch_bounds__(256) main_kernel(const float* __restrict__ x,
                                                   const float* __restrict__ P,
                                                   float* __restrict__ out) {
    const int b   = blockIdx.x;
    const int bc  = blockIdx.y;
    const int idx0 = threadIdx.x * 4;          // 0..1020
    const int g   = b * 1024 + idx0;           // base output (mod 4 == 0)
    const float* xb = x + (size_t)bc * T_IN;
    const float* Pb = P + (size_t)bc * NSEG * 8;
    float* ob = out + (size_t)bc * T_IN;
    const float C23 = 2.0f / 3.0f;

    if (b >= 4 && b <= 426) {
        // ---- fast path: branch-free, no reflection, frames in range ----
        const int jlo = b + (idx0 >= 512 ? 1 : 0);   // wave-uniform
        const int pos = g + POS0;                    // always even
        // E/O recombination (scaled by 2/3): even-i outputs use O, odd-i use E
        float pE[4], pO[4];
        #pragma unroll
        for (int jj = 0; jj < 4; ++jj) {
            const float* q = Pb + (jlo + jj) * 8;
            pE[jj] = C23 * (q[0] + q[10] + q[20] + q[30]);
            pO[jj] = C23 * (q[1] + q[11] + q[21] + q[31]);
        }
        // window generators: theta_i = 2*pi*((pos+i) mod 4096)/4096
        const float frac = (float)(pos & 4095) * (1.0f / 4096.0f);
        const float cs0 = COS2PI(frac), sn0 = SIN2PI(frac);
        const float cs[4] = { cs0, fmaf(cs0, CD1, -sn0 * SD1),
                                   fmaf(cs0, CD2, -sn0 * SD2),
                                   fmaf(cs0, CD3, -sn0 * SD3) };
        const float sn[4] = { sn0, fmaf(sn0, CD1,  cs0 * SD1),
                                   fmaf(sn0, CD2,  cs0 * SD2),
                                   fmaf(sn0, CD3,  cs0 * SD3) };
        const float K = 4096.0f / 3.0f;              // 2048 * 2/3
        float acc0=0, acc1=0, acc2=0, acc3=0;
        #pragma unroll
        for (int jj = 0; jj < 4; ++jj) {
            const int j  = jlo + jj;
            const int ph = j & 3;                    // half-block-uniform
            const int m3 = 2048 * j - 3072 - g - 3;  // x[m3..m3+3], reversed use
            const float xv3 = xb[m3 + 0];            // -> output i=3
            const float xv2 = xb[m3 + 1];
            const float xv1 = xb[m3 + 2];
            const float xv0 = xb[m3 + 3];            // -> output i=0
            // win[t_i] = 0.5 -/+ 0.5 * (cs|sn)[i] per ph
            #pragma unroll
            for (int i = 0; i < 4; ++i) {
                const float base = (ph & 1) ? sn[i] : cs[i];
                const float w = (ph & 2) ? fmaf(0.5f, base, 0.5f)
                                         : fmaf(-0.5f, base, 0.5f);
                const float xv = (i == 0) ? xv0 : (i == 1) ? xv1 : (i == 2) ? xv2 : xv3;
                const float pp = (i & 1) ? pE[jj] : pO[jj];
                const float term = fmaf(K * w, xv, pp);
                if      (i == 0) acc0 = fmaf(w, term, acc0);
                else if (i == 1) acc1 = fmaf(w, term, acc1);
                else if (i == 2) acc2 = fmaf(w, term, acc2);
                else             acc3 = fmaf(w, term, acc3);
            }
        }
        *reinterpret_cast<float4*>(ob + g) = make_float4(acc0, acc1, acc2, acc3);
    } else {
        // ---- slow path: edges, full clamping + reflection ----
        #pragma unroll
        for (int i = 0; i < 4; ++i) {
            const int gg = g + i;
            if (gg >= T_IN) continue;
            const int pos = gg + POS0;
            int jh = pos >> 10, jl = jh - 3;
            if (jl < F_LO) jl = F_LO;
            if (jh > F_HI) jh = F_HI;
            const int slot = (pos & 1) ^ 1;          // odd pos -> E(0), even -> O(1)
            float acc = 0.0f;
            for (int j = jl; j <= jh; ++j) {
                const int t = pos - (j << 10);       // 0..4095
                const float w = fmaf(-0.5f, COS2PI((float)t * (1.0f / 4096.0f)), 0.5f);
                const float xv = xb[map_idx(j * HOP + (NFFT - t))];
                const float* q = Pb + j * 8 + slot;
                const float p = q[0] + q[10] + q[20] + q[30];
                acc += w * (2048.0f * w * xv + p);
            }
            ob[gg] = acc * C23;
        }
    }
}

extern "C" void kernel_launch(void* const* d_in, const int* in_sizes, int n_in,
                              void* d_out, int out_size, void* d_ws, size_t ws_size,
                              hipStream_t stream) {
    const float* x = (const float*)d_in[0];   // mix (8,2,441000) fp32
    float* out = (float*)d_out;
    float* Pw  = (float*)d_ws;                // BC*NSEG*8 floats (~218 KB)

    seg_partials_kernel<<<dim3(109, BC), 256, 0, stream>>>(x, Pw);
    main_kernel<<<dim3(431, BC), 256, 0, stream>>>(x, Pw, out);
}

// Round 5
// 26.988 us; speedup vs baseline: 1.3909x; 1.3909x over previous
//
#include <hip/hip_runtime.h>

// Fixed problem constants
#define T_IN  441000          // samples per (b,c)
#define L1    444416          // after 1st reflect pad
#define PAD1  1536
#define P2    2048
#define POS0  3584            // output g -> pad position g + 3584
#define NB    216             // ceil(441000/2048) output blocks per bc
#define BC    16              // B*C
#define NWG   (NB * BC)       // 3456 = 8*432 (XCD-swizzle exact)

// sin/cos of 2*pi*f, f in revolutions
#if __has_builtin(__builtin_amdgcn_cosf)
#define COS2PI(f) __builtin_amdgcn_cosf(f)
#define SIN2PI(f) __builtin_amdgcn_sinf(f)
#else
#define COS2PI(f) __cosf(6.28318530717958647692f * (f))
#define SIN2PI(f) __sinf(6.28318530717958647692f * (f))
#endif

// Composed reflect-pads: xpad[m] = x[map_idx(m)]
__device__ __forceinline__ int map_idx(int m) {
    int a = m - P2;
    if (a < 0) a = -a;
    else if (a >= L1) a = 2 * L1 - 2 - a;
    int b = a - PAD1;
    if (b < 0) b = -b;
    else if (b >= T_IN) b = 2 * T_IN - 2 - b;
    return b;
}

// One fused kernel: stage x-span -> frame E/O sums -> outputs.
// Block covers outputs [2048B, 2048B+2047] of slice bc; frames j in [2B, 2B+5];
// pad-coord span [2048B, 2048B+9216] staged in LDS.
__global__ void __launch_bounds__(512) fused_kernel(const float* __restrict__ x,
                                                    float* __restrict__ out) {
    __shared__ __align__(16) float xs[9220];   // 9217 used
    __shared__ float red[6][2][8];
    __shared__ float pEO[2][6];                // [0]=E (even-n), [1]=O, scaled 2/3

    // XCD-aware swizzle (bijective: NWG = 8*432)
    const int lin = blockIdx.x;
    const int wg  = (lin & 7) * (NWG / 8) + (lin >> 3);
    const int B   = wg % NB;
    const int bc  = wg / NB;
    const int tid = threadIdx.x;
    const float* xb = x + (size_t)bc * T_IN;
    float*       ob = out + (size_t)bc * T_IN;
    const bool fast = (B >= 2 && B <= 212);
    const int padbase = 2048 * B;

    // ---- Phase 1: stage xs[i] = xpad[padbase + i], i in [0, 9216] ----
    if (fast) {
        const float* src = xb + (padbase - POS0);     // identity region, 16B-aligned
        #pragma unroll
        for (int i4 = 0; i4 < 4; ++i4) {
            const int idx = (tid + 512 * i4) * 4;
            *reinterpret_cast<float4*>(&xs[idx]) =
                *reinterpret_cast<const float4*>(&src[idx]);
        }
        if (tid < 256) {
            const int idx = 8192 + tid * 4;
            *reinterpret_cast<float4*>(&xs[idx]) =
                *reinterpret_cast<const float4*>(&src[idx]);
        } else if (tid == 256) {
            xs[9216] = src[9216];
        }
    } else {
        for (int i = tid; i <= 9216; i += 512)
            xs[i] = xb[map_idx(padbase + i)];
    }
    __syncthreads();

    // ---- per-thread sincos, shared by phases 2 and 3 ----
    const float c0 = COS2PI((float)tid * (1.0f / 4096.0f));
    const float s0 = SIN2PI((float)tid * (1.0f / 4096.0f));
    const float Hh = 0.70710678118654752440f;
    const float c1 = (c0 - s0) * Hh;   // cos(theta + pi/4)
    const float s1 = (s0 + c0) * Hh;   // sin(theta + pi/4)

    // ---- Phase 2: frame E/O partial sums ----
    // sample i = tid + 512*c4; frame m = (i>>10) - q; win(1024q + r) from quarter formula
    float acc[6] = {0, 0, 0, 0, 0, 0};
    #pragma unroll
    for (int c4 = 0; c4 < 18; ++c4) {
        const float cA = (c4 & 1) ? c1 : c0;
        const float sA = (c4 & 1) ? s1 : s0;
        const int c = c4 >> 1;
        const float xv = xs[tid + 512 * c4];
        #pragma unroll
        for (int q = 0; q < 4; ++q) {
            const int m = c - q;
            if (m < 0 || m > 5) continue;
            const float w = (q == 0) ? fmaf(-0.5f, cA, 0.5f)
                          : (q == 1) ? fmaf( 0.5f, sA, 0.5f)
                          : (q == 2) ? fmaf( 0.5f, cA, 0.5f)
                          :            fmaf(-0.5f, sA, 0.5f);
            acc[m] = fmaf(xv, w, acc[m]);
        }
    }
    {
        const int wave = tid >> 6, lane = tid & 63;
        #pragma unroll
        for (int m = 0; m < 6; ++m) {
            float s = acc[m];
            s += __shfl_down(s, 32, 64);
            s += __shfl_down(s, 16, 64);
            s += __shfl_down(s,  8, 64);
            s += __shfl_down(s,  4, 64);
            s += __shfl_down(s,  2, 64);   // parity preserved: lane0=even-n, lane1=odd-n
            if (lane < 2) red[m][lane][wave] = s;
        }
    }
    __syncthreads();
    if (tid < 12) {
        const int m = tid >> 1, par = tid & 1;
        float s = 0.0f;
        #pragma unroll
        for (int w = 0; w < 8; ++w) s += red[m][par][w];
        pEO[par][m] = s * (2.0f / 3.0f);
    }
    __syncthreads();

    // ---- Phase 3: outputs ----
    const float K = 4096.0f / 3.0f;               // 2048 * 2/3
    if (fast) {
        // 8 window phases w_p = .5 - .5*cos(theta0 + p*pi/4)
        const float cosv[8] = { c0, c1, -s0, -s1, -c0, -c1, s0, s1 };
        float wph[8], kw[8];
        #pragma unroll
        for (int p = 0; p < 8; ++p) {
            wph[p] = fmaf(-0.5f, cosv[p], 0.5f);
            kw[p]  = K * wph[p];
        }
        float psel[6];
        #pragma unroll
        for (int m = 0; m < 6; ++m)
            psel[m] = (tid & 1) ? pEO[0][m] : pEO[1][m];   // pos parity == tid parity
        #pragma unroll
        for (int k = 0; k < 4; ++k) {
            const int off = (k == 0) ? 0 : (k == 3) ? 2 : 1;   // jlo - 2B, compile-time
            float a = 0.0f;
            #pragma unroll
            for (int jj = 0; jj < 4; ++jj) {
                const int m = off + jj;
                const int p = (7 + k - 2 * m) & 7;             // window phase index
                const float xv = xs[2048 * m + 512 - tid - 512 * k];
                a = fmaf(wph[p], fmaf(kw[p], xv, psel[m]), a);
            }
            ob[padbase + tid + 512 * k] = a;
        }
    } else {
        #pragma unroll
        for (int k = 0; k < 4; ++k) {
            const int gl = tid + 512 * k;
            const int g  = padbase + gl;
            if (g >= T_IN) continue;
            const int pos = g + POS0;
            int jh = pos >> 10, jl = jh - 3;
            if (jl < 2)   jl = 2;
            if (jh > 432) jh = 432;
            float a = 0.0f;
            for (int j = jl; j <= jh; ++j) {
                const int m = j - 2 * B;                       // 0..5
                const int t = pos - (j << 10);                 // 0..4095
                const float w = fmaf(-0.5f, COS2PI((float)t * (1.0f / 4096.0f)), 0.5f);
                const float xv = xs[2048 * m + 512 - gl];
                const float p  = (pos & 1) ? pEO[0][m] : pEO[1][m];
                a = fmaf(w, fmaf(K * w, xv, p), a);
            }
            ob[g] = a;
        }
    }
}

extern "C" void kernel_launch(void* const* d_in, const int* in_sizes, int n_in,
                              void* d_out, int out_size, void* d_ws, size_t ws_size,
                              hipStream_t stream) {
    const float* x = (const float*)d_in[0];   // mix (8,2,441000) fp32
    float* out = (float*)d_out;
    fused_kernel<<<dim3(NWG), 512, 0, stream>>>(x, out);
}

// Round 6
// 24.464 us; speedup vs baseline: 1.5343x; 1.1031x over previous
//
#include <hip/hip_runtime.h>

// Fixed problem constants
#define T_IN  441000          // samples per (b,c)
#define L1    444416          // after 1st reflect pad
#define PAD1  1536
#define P2    2048
#define POS0  3584            // output g -> pad position g + 3584
#define NB    108             // ceil(441000/4096) output blocks per bc
#define BC    16              // B*C
#define NWG   (NB * BC)       // 1728 = 8*216 (bijective XCD swizzle)

// sin/cos of 2*pi*f, f in revolutions
#if __has_builtin(__builtin_amdgcn_cosf)
#define COS2PI(f) __builtin_amdgcn_cosf(f)
#define SIN2PI(f) __builtin_amdgcn_sinf(f)
#else
#define COS2PI(f) __cosf(6.28318530717958647692f * (f))
#define SIN2PI(f) __sinf(6.28318530717958647692f * (f))
#endif

// Composed reflect-pads: xpad[m] = x[map_idx(m)]
__device__ __forceinline__ int map_idx(int m) {
    int a = m - P2;
    if (a < 0) a = -a;
    else if (a >= L1) a = 2 * L1 - 2 - a;
    int b = a - PAD1;
    if (b < 0) b = -b;
    else if (b >= T_IN) b = 2 * T_IN - 2 - b;
    return b;
}

// One fused kernel. Block = 4096 outputs [4096B, 4096B+4095] of slice bc.
// Frames j in [4B, 4B+7] (m = j-4B in [0,7]); pad-span [4096B, 4096B+11264] in LDS.
// Phase 2 key identity: sample i = tid + 512*c4 contributes to frame m with window
// win[i-1024m] = 0.5 - 0.5*cos(theta_tid + ((c4&1) + 2q)*pi/4), q = (c4>>1)-m —
// only 8 per-thread window constants (wqE/wqO), iteration-invariant.
__global__ void __launch_bounds__(512, 6) fused_kernel(const float* __restrict__ x,
                                                       float* __restrict__ out) {
    __shared__ __align__(16) float xs[11268];   // 11265 used
    __shared__ float red[8][2][8];
    __shared__ float pEO[2][8];                 // [0]=E (even-n), [1]=O; scaled 2/3

    const int lin = blockIdx.x;
    const int wg  = (lin & 7) * (NWG / 8) + (lin >> 3);   // XCD swizzle (bijective)
    const int B   = wg % NB;
    const int bc  = wg / NB;
    const int tid = threadIdx.x;
    const float* xb = x + (size_t)bc * T_IN;
    float*       ob = out + (size_t)bc * T_IN;
    const int padbase = 4096 * B;
    const bool fast = (B >= 1 && B <= 105);     // identity map over whole span

    // ---- Phase 1: stage xs[i] = xpad[padbase + i], i in [0, 11264] ----
    if (fast) {
        const float* src = xb + (padbase - POS0);   // 16B-aligned (padbase-3584 ≡ 0 mod 4)
        #pragma unroll
        for (int i4 = 0; i4 < 5; ++i4) {
            const int idx = (tid + 512 * i4) * 4;
            *reinterpret_cast<float4*>(&xs[idx]) =
                *reinterpret_cast<const float4*>(&src[idx]);
        }
        if (tid < 256) {
            const int idx = (tid + 2560) * 4;       // floats 10240..11263
            *reinterpret_cast<float4*>(&xs[idx]) =
                *reinterpret_cast<const float4*>(&src[idx]);
        } else if (tid == 256) {
            xs[11264] = src[11264];
        }
    } else {
        for (int i = tid; i <= 11264; i += 512)
            xs[i] = xb[map_idx(padbase + i)];
    }

    // per-thread sincos (independent of staging; hides under loads)
    const float c0 = COS2PI((float)tid * (1.0f / 4096.0f));
    const float s0 = SIN2PI((float)tid * (1.0f / 4096.0f));
    const float Hh = 0.70710678118654752440f;
    const float c1 = (c0 - s0) * Hh;   // cos(theta + pi/4)
    const float s1 = (s0 + c0) * Hh;   // sin(theta + pi/4)
    // quarter-window constants: win at phase offsets u*pi/4
    const float wqE[4] = { fmaf(-0.5f, c0, 0.5f), fmaf( 0.5f, s0, 0.5f),
                           fmaf( 0.5f, c0, 0.5f), fmaf(-0.5f, s0, 0.5f) };
    const float wqO[4] = { fmaf(-0.5f, c1, 0.5f), fmaf( 0.5f, s1, 0.5f),
                           fmaf( 0.5f, c1, 0.5f), fmaf(-0.5f, s1, 0.5f) };
    __syncthreads();

    // ---- Phase 2: frame E/O partial sums (64 fma + 22 LDS loads / thread) ----
    float acc[8] = {0, 0, 0, 0, 0, 0, 0, 0};
    #pragma unroll
    for (int c4 = 0; c4 < 22; ++c4) {
        const int c = c4 >> 1;
        const float xv = xs[tid + 512 * c4];
        #pragma unroll
        for (int q = 0; q < 4; ++q) {
            const int m = c - q;
            if (m < 0 || m > 7) continue;
            const float w = (c4 & 1) ? wqO[q] : wqE[q];   // compile-time select
            acc[m] = fmaf(xv, w, acc[m]);
        }
    }
    {
        const int wave = tid >> 6, lane = tid & 63;
        #pragma unroll
        for (int m = 0; m < 8; ++m) {
            float s = acc[m];
            s += __shfl_down(s, 32, 64);
            s += __shfl_down(s, 16, 64);
            s += __shfl_down(s,  8, 64);
            s += __shfl_down(s,  4, 64);
            s += __shfl_down(s,  2, 64);   // parity preserved: lane0=even-n, lane1=odd-n
            if (lane < 2) red[m][lane][wave] = s;
        }
    }
    __syncthreads();
    if (tid < 16) {
        const int m = tid >> 1, par = tid & 1;
        float s = 0.0f;
        #pragma unroll
        for (int w = 0; w < 8; ++w) s += red[m][par][w];
        pEO[par][m] = s * (2.0f / 3.0f);
    }
    __syncthreads();

    // ---- Phase 3: outputs. out[g] = sum_j wph * (K*wph*xs[direct] + pEO) ----
    const float K = 4096.0f / 3.0f;               // 2048 * 2/3
    if (fast) {
        // cosv[u] = cos(theta_tid + u*pi/4)
        const float cosv[8] = { c0, c1, -s0, -s1, -c0, -c1, s0, s1 };
        float wph[8], kw[8];
        #pragma unroll
        for (int p = 0; p < 8; ++p) {
            wph[p] = fmaf(-0.5f, cosv[p], 0.5f);
            kw[p]  = K * wph[p];
        }
        float psel[8];
        #pragma unroll
        for (int m = 0; m < 8; ++m)
            psel[m] = (tid & 1) ? pEO[0][m] : pEO[1][m];  // pos parity == tid parity
        #pragma unroll
        for (int k = 0; k < 8; ++k) {
            const int off = (k + 1) >> 1;                 // jlo - 4B, compile-time
            float a = 0.0f;
            #pragma unroll
            for (int jj = 0; jj < 4; ++jj) {
                const int m = off + jj;                   // 0..7, compile-time
                const int u = (k & 1) ? (6 - 2 * jj) : (7 - 2 * jj);
                const float xv = xs[2048 * m + 512 - tid - 512 * k];
                a = fmaf(wph[u], fmaf(kw[u], xv, psel[m]), a);
            }
            ob[padbase + tid + 512 * k] = a;
        }
    } else {
        #pragma unroll
        for (int k = 0; k < 8; ++k) {
            const int gl = tid + 512 * k;
            const int g  = padbase + gl;
            if (g >= T_IN) continue;
            const int pos = g + POS0;
            int jh = pos >> 10, jl = jh - 3;
            if (jl < 2)   jl = 2;
            if (jh > 432) jh = 432;
            float a = 0.0f;
            for (int j = jl; j <= jh; ++j) {
                const int m = j - 4 * B;                  // staged frame slot
                const int t = pos - (j << 10);            // 0..4095
                const float w = fmaf(-0.5f, COS2PI((float)t * (1.0f / 4096.0f)), 0.5f);
                const float xv = xs[2048 * m + 512 - gl];
                const float p  = (pos & 1) ? pEO[0][m] : pEO[1][m];
                a = fmaf(w, fmaf(K * w, xv, p), a);
            }
            ob[g] = a;
        }
    }
}

extern "C" void kernel_launch(void* const* d_in, const int* in_sizes, int n_in,
                              void* d_out, int out_size, void* d_ws, size_t ws_size,
                              hipStream_t stream) {
    const float* x = (const float*)d_in[0];   // mix (8,2,441000) fp32
    float* out = (float*)d_out;
    fused_kernel<<<dim3(NWG), 512, 0, stream>>>(x, out);
}